// Round 12
// baseline (319.705 us; speedup 1.0000x reference)
//
#include <hip/hip_runtime.h>
#include <hip/hip_bf16.h>

// TT-linear: out(8192x4096) = x @ W, W from TT cores g1,g2.
// R12 = R11 with the kk1 A-address bug fixed: kk1 swizzled offset is XOR 64,
//   not ADD 64 (ADD carried into row bits for lanes with cO>=64 -> garbage).
// Design: B never touches LDS — prep writes W pre-swizzled in MFMA-fragment
//   order (1KB/frag, lane-contiguous); GEMM loads B global->VGPR (coalesced,
//   dbuf 1 phase ahead). LDS = A only: [256][64]bf16 tiles, 128B rows,
//   chunk^(row&7) swizzle (R7-verified 0-conflict), 4-buffer ring, staged 3
//   tiles ahead, asm ds_read read-ahead + counted lgkmcnt(8)/vmcnt(8).

#define TOKENS 8192
#define KDIM 4096
#define NDIM 4096

typedef __attribute__((ext_vector_type(8))) __bf16 bf16x8;
typedef __attribute__((ext_vector_type(4))) float f32x4;
typedef __attribute__((ext_vector_type(8))) unsigned short u16x8;

typedef __attribute__((address_space(1))) unsigned int as1_uint;
typedef __attribute__((address_space(3))) unsigned int as3_uint;

#define GLOAD_LDS16(gp, lp) \
  __builtin_amdgcn_global_load_lds((as1_uint*)(void*)(gp), (as3_uint*)(void*)(lp), 16, 0, 0)

#define BAR() asm volatile("s_barrier" ::: "memory")
#define VMCNT8() asm volatile("s_waitcnt vmcnt(8)" ::: "memory")
#define VMCNT0() asm volatile("s_waitcnt vmcnt(0)" ::: "memory")
#define LGKM8() asm volatile("s_waitcnt lgkmcnt(8)" ::: "memory")

__device__ inline unsigned short f2bf(float f) {
  __hip_bfloat16 h = __float2bfloat16(f);
  return __builtin_bit_cast(unsigned short, h);
}

// ---------------- Kernel 1: prep ----------------
// blocks [0,16384): cvt x -> bf16 (Xb). blocks [16384,20480): build one n-column
// of W, written PRE-SWIZZLED into fragment order:
//   frag f = (bn*128 + s)*16 + wn*4 + j ; lane l = kg*16 + col holds 16B at l*16:
//   8 bf16 with k = s*32 + kg*8 + e, n = bn*256 + wn*64 + j*16 + col.
__global__ __launch_bounds__(256) void prep_kernel(const float* __restrict__ x,
                                                   const float* __restrict__ g1,
                                                   const float* __restrict__ g2,
                                                   unsigned short* __restrict__ xb,
                                                   unsigned short* __restrict__ wtp) {
  __shared__ float a_s[64 * 16];  // [m1][r] for fixed n1
  __shared__ float b_s[16 * 64];  // [r][m2] for fixed n2
  const int bid = blockIdx.x;
  const int t = threadIdx.x;

  if (bid < 16384) {
    size_t i = (size_t)bid * 256 + t;
    const float4* p = reinterpret_cast<const float4*>(x) + i * 2;
    float4 v0 = p[0];
    float4 v1 = p[1];
    u16x8 u;
    u[0] = f2bf(v0.x); u[1] = f2bf(v0.y); u[2] = f2bf(v0.z); u[3] = f2bf(v0.w);
    u[4] = f2bf(v1.x); u[5] = f2bf(v1.y); u[6] = f2bf(v1.z); u[7] = f2bf(v1.w);
    reinterpret_cast<u16x8*>(xb)[i] = u;
    return;
  }

  const int n = bid - 16384;
  const int n1 = n >> 6, n2 = n & 63;
  for (int e = t; e < 1024; e += 256) {
    int m1 = e >> 4, r = e & 15;
    a_s[e] = g1[m1 * 1024 + n1 * 16 + r];
  }
  for (int e = t; e < 1024; e += 256) {
    int r = e >> 6, m2 = e & 63;
    b_s[e] = g2[r * 4096 + m2 * 64 + n2];
  }
  __syncthreads();

  unsigned short loc[16];
  const int kbase = t * 16;
#pragma unroll
  for (int kk = 0; kk < 16; ++kk) {
    int k = kbase + kk;
    int m1 = k >> 6, m2 = k & 63;
    float acc = 0.f;
#pragma unroll
    for (int r = 0; r < 16; ++r) acc += a_s[m1 * 16 + r] * b_s[r * 64 + m2];
    loc[kk] = f2bf(acc);
  }
  // swizzled write: thread t covers k = t*16..t*16+15 => s = t>>1, kg0 = (t&1)*2
  const int col = n & 15, j = (n >> 4) & 3, wn = (n >> 6) & 3, bn = n >> 8;
  const int s = t >> 1;
  const int kg0 = (t & 1) * 2;
  size_t fbase = (((size_t)bn * 128 + s) * 16 + wn * 4 + j) * 512;
  *(u16x8*)(wtp + fbase + (kg0 * 16 + col) * 8) = *reinterpret_cast<u16x8*>(&loc[0]);
  *(u16x8*)(wtp + fbase + ((kg0 + 1) * 16 + col) * 8) = *reinterpret_cast<u16x8*>(&loc[8]);
}

// ---------------- Kernel 2: GEMM 256x256, A-only LDS ring, B global->reg ----------------
// Phase p (= 32-k step, 128 phases, A-tile T = p>>1, half kk = p&1):
//   issue: 8 asm ds_read (A frags for phase p+1) ; 4 B loads (step p+1) ;
//          2 A gloads (tile T+3) ; VMCNT8 ; LGKM8 ; sched_barrier ;
//          setprio1 ; 32 MFMA (sets (p&1)) ; setprio0 ; BAR.
// A-visibility: tile staged @phases 2T..2T+1, stager-side vmcnt-drained by
//   @2T+3, barrier, first read @2T+5 (>=1-barrier margin).
// WAR: stage tile T+3 -> buf (T+3)&3 = buf of T-1; T-1's last ds_reads issued
//   @2T-1 completed at @2T's LGKM8 (only 8 newer outstanding), barriers between.
__global__ __launch_bounds__(512, 1) void gemm_kernel(const unsigned short* __restrict__ Xb,
                                                      const unsigned short* __restrict__ WtP,
                                                      float* __restrict__ out) {
  __shared__ __align__(16) char lds[131072];

  const int t = threadIdx.x;
  const int lane = t & 63;
  const int wave = t >> 6;   // 0..7
  const int wm = wave >> 2;  // 0..1 : 128 output rows
  const int wn = wave & 3;   // 0..3 : 64 output cols

  // 8x8-per-XCD chunking
  const int bid = blockIdx.x;
  const int xcd = bid & 7, jj = bid >> 3;
  const int bm = ((xcd >> 1) << 3) + (jj >> 3);
  const int bn = ((xcd & 1) << 3) + (jj & 7);
  const int m0 = bm << 8, n0 = bn << 8;

  // A staging: thread t -> row t>>3 within 64-row gload group, lds chunk t&7,
  // inverse-swizzled source chunk (t&7)^((t>>3)&7).
  const int srow = t >> 3;
  const int csrc = (t & 7) ^ ((t >> 3) & 7);
  const unsigned short* aS = Xb + (size_t)(m0 + srow) * KDIM + csrc * 8;
  const int ldsW = wave << 10;  // wave-uniform 1KB slot

#define STG1(kt, bb, g) \
  GLOAD_LDS16(aS + (size_t)(g) * 64 * KDIM + (size_t)(kt) * 64, lds + (bb) + (g) * 8192 + ldsW)
#define STG2(kt, bb, gg) do { STG1(kt, bb, (gg) * 2); STG1(kt, bb, (gg) * 2 + 1); } while (0)

  // A fragment reads: row = wm*128 + i*16 + (lane&15); kk0 chunk = lane>>4,
  // kk1 chunk = 4 + (lane>>4); lds chunk = chunk ^ (lane&7).
  // kk1 = byte XOR 64 on the swizzled offset (NOT add — R11 bug).
  const int cO = ((lane >> 4) ^ (lane & 7)) << 4;
  const int aOff = (wm * 128 + (lane & 15)) * 128 + cO;
  const unsigned aAddrK0 = (unsigned)(size_t)(lds + aOff);
  const unsigned aAddrK1 = (unsigned)(size_t)(lds + (aOff ^ 64));

  // B direct loads: frag (s,j) at bP + s*8192 + j*512 (shorts), lane-contiguous
  const unsigned short* bP = WtP + (((size_t)bn * 128) * 16 + (size_t)wn * 4) * 512 + lane * 8;

  bf16x8 fA[2][8], fB[2][4];

#define DSR(dst, base, off) \
  asm volatile("ds_read_b128 %0, %1 offset:" #off : "=&v"(dst) : "v"(base))
#define RDP(P, RB, AA) do { \
    unsigned _ab = (AA) + (RB); \
    DSR(fA[P][0], _ab, 0);     DSR(fA[P][1], _ab, 2048); \
    DSR(fA[P][2], _ab, 4096);  DSR(fA[P][3], _ab, 6144); \
    DSR(fA[P][4], _ab, 8192);  DSR(fA[P][5], _ab, 10240); \
    DSR(fA[P][6], _ab, 12288); DSR(fA[P][7], _ab, 14336); \
  } while (0)

#define LDB(P, s) do { \
    const unsigned short* _b = bP + (size_t)(s) * 8192; \
    fB[P][0] = *(const bf16x8*)(_b); \
    fB[P][1] = *(const bf16x8*)(_b + 512); \
    fB[P][2] = *(const bf16x8*)(_b + 1024); \
    fB[P][3] = *(const bf16x8*)(_b + 1536); \
  } while (0)

#define MF(i, j, P) acc[i][j] = __builtin_amdgcn_mfma_f32_16x16x32_bf16(fA[P][i], fB[P][j], acc[i][j], 0, 0, 0)
#define MMP(P) do { \
    MF(0, 0, P); MF(0, 1, P); MF(0, 2, P); MF(0, 3, P); \
    MF(1, 0, P); MF(1, 1, P); MF(1, 2, P); MF(1, 3, P); \
    MF(2, 0, P); MF(2, 1, P); MF(2, 2, P); MF(2, 3, P); \
    MF(3, 0, P); MF(3, 1, P); MF(3, 2, P); MF(3, 3, P); \
    MF(4, 0, P); MF(4, 1, P); MF(4, 2, P); MF(4, 3, P); \
    MF(5, 0, P); MF(5, 1, P); MF(5, 2, P); MF(5, 3, P); \
    MF(6, 0, P); MF(6, 1, P); MF(6, 2, P); MF(6, 3, P); \
    MF(7, 0, P); MF(7, 1, P); MF(7, 2, P); MF(7, 3, P); \
  } while (0)

  f32x4 acc[8][4];
#pragma unroll
  for (int i = 0; i < 8; ++i)
#pragma unroll
    for (int j = 0; j < 4; ++j) acc[i][j] = (f32x4){0.f, 0.f, 0.f, 0.f};

  // ---- prologue: A tiles 0,1,2 -> bufs 0,1,2; B(0); drain; read phase-0 frags ----
  STG2(0, 0, 0); STG2(0, 0, 1);
  STG2(1, 32768, 0); STG2(1, 32768, 1);
  STG2(2, 65536, 0); STG2(2, 65536, 1);
  LDB(0, 0);
  VMCNT0();
  BAR();
  RDP(0, 0, aAddrK0);  // tile 0, kk0 -> fA[0] (for phase 0)

#pragma unroll 1
  for (int u = 0; u < 64; ++u) {
    const int rbA = (u & 3) << 15;          // buf of tile u
    const int rbA1 = ((u + 1) & 3) << 15;   // buf of tile u+1
    const int sbA = ((u + 3) & 3) << 15;    // stage buf (tile u+3)
    const int ktS = (u + 3) & 63;           // staged tile (wraps to dummy at tail)

    // ---- phase 2u: MFMA(set0: tile u kk0); read tile u kk1; load B(2u+1); stage g0,1 ----
    RDP(1, rbA, aAddrK1);
    LDB(1, 2 * u + 1);
    STG2(ktS, sbA, 0);
    VMCNT8();
    LGKM8();
    __builtin_amdgcn_sched_barrier(0);
    __builtin_amdgcn_s_setprio(1);
    MMP(0);
    __builtin_amdgcn_s_setprio(0);
    BAR();

    // ---- phase 2u+1: MFMA(set1); read tile u+1 kk0; load B(2u+2); stage g2,3 ----
    RDP(0, rbA1, aAddrK0);
    LDB(0, (2 * u + 2) & 127);              // wraps to dummy at u=63
    STG2(ktS, sbA, 1);
    VMCNT8();
    LGKM8();
    __builtin_amdgcn_sched_barrier(0);
    __builtin_amdgcn_s_setprio(1);
    MMP(1);
    __builtin_amdgcn_s_setprio(0);
    BAR();
  }

  // ---- epilogue: C/D layout col = lane&15, row = (lane>>4)*4 + q ----
  const int crow = (lane >> 4) << 2;
  const int ccol = lane & 15;
#pragma unroll
  for (int i = 0; i < 8; ++i) {
#pragma unroll
    for (int j = 0; j < 4; ++j) {
      size_t base = (size_t)(m0 + wm * 128 + i * 16 + crow) * NDIM + (n0 + wn * 64 + j * 16 + ccol);
#pragma unroll
      for (int q = 0; q < 4; ++q) out[base + (size_t)q * NDIM] = acc[i][j][q];
    }
  }
}

extern "C" void kernel_launch(void* const* d_in, const int* in_sizes, int n_in,
                              void* d_out, int out_size, void* d_ws, size_t ws_size,
                              hipStream_t stream) {
  const float* x = (const float*)d_in[0];
  const float* g1 = (const float*)d_in[1];
  const float* g2 = (const float*)d_in[2];
  float* out = (float*)d_out;

  unsigned short* WtP = (unsigned short*)d_ws;
  unsigned short* Xb = (unsigned short*)d_ws + (size_t)KDIM * NDIM;

  prep_kernel<<<16384 + NDIM, 256, 0, stream>>>(x, g1, g2, Xb, WtP);
  gemm_kernel<<<(TOKENS / 256) * (NDIM / 256), 512, 0, stream>>>(Xb, WtP, out);
}